// Round 1
// baseline (431.902 us; speedup 1.0000x reference)
//
#include <hip/hip_runtime.h>

#define N_TOTAL 409600

// Pre-transpose weight [Cout][Cin][3][3][3] -> wt[tap][cin][cout] so the
// hot-loop weight index is wave-uniform AND consecutive in cout -> compiler
// emits wide scalar loads (s_load_dwordx4) that co-issue with the VALU FMAs.
__global__ __launch_bounds__(256) void wt_transpose(const float* __restrict__ w,
                                                    float* __restrict__ wt) {
    int i = blockIdx.x * 256 + threadIdx.x;  // 16*16*27 = 6912
    if (i < 6912) {
        int co  = i / 432;          // 432 = 16*27
        int r   = i - co * 432;
        int ci  = r / 27;
        int tap = r - ci * 27;
        wt[(tap * 16 + ci) * 16 + co] = w[i];
    }
}

template <int R>
__global__ __launch_bounds__(256) void conv_level(const float* __restrict__ in,
                                                  const float* __restrict__ wt,
                                                  const float* __restrict__ bias,
                                                  float* __restrict__ out,
                                                  int base) {
    const int v = blockIdx.x * 256 + threadIdx.x;   // voxel index within level
    const int b = blockIdx.y;

    const int w = v % R;
    const int h = (v / R) % R;
    const int d = v / (R * R);

    const size_t lvl = ((size_t)b * N_TOTAL + base) * 16;
    const float* __restrict__ inp = in + lvl;

    float acc[16];
#pragma unroll
    for (int co = 0; co < 16; ++co) acc[co] = bias[co];   // uniform -> s_load

    for (int kd = 0; kd < 3; ++kd) {
        const int zd = d + kd - 1;
        if ((unsigned)zd >= (unsigned)R) continue;
        for (int kh = 0; kh < 3; ++kh) {
            const int zh = h + kh - 1;
            if ((unsigned)zh >= (unsigned)R) continue;
#pragma unroll
            for (int kw = 0; kw < 3; ++kw) {
                const int zw = w + kw - 1;
                if ((unsigned)zw >= (unsigned)R) continue;

                const float* src = inp + (size_t)(((zd * R + zh) * R) + zw) * 16;
                const float4* p4 = reinterpret_cast<const float4*>(src);
                float4 q0 = p4[0], q1 = p4[1], q2 = p4[2], q3 = p4[3];
                float x[16];
                x[0]  = q0.x; x[1]  = q0.y; x[2]  = q0.z; x[3]  = q0.w;
                x[4]  = q1.x; x[5]  = q1.y; x[6]  = q1.z; x[7]  = q1.w;
                x[8]  = q2.x; x[9]  = q2.y; x[10] = q2.z; x[11] = q2.w;
                x[12] = q3.x; x[13] = q3.y; x[14] = q3.z; x[15] = q3.w;

                const float* wp = wt + ((kd * 3 + kh) * 3 + kw) * 256;
#pragma unroll
                for (int ci = 0; ci < 16; ++ci) {
#pragma unroll
                    for (int co = 0; co < 16; ++co) {
                        acc[co] = fmaf(x[ci], wp[ci * 16 + co], acc[co]);
                    }
                }
            }
        }
    }

    float* dst = out + lvl + (size_t)v * 16;
    float4* d4 = reinterpret_cast<float4*>(dst);
    d4[0] = make_float4(acc[0],  acc[1],  acc[2],  acc[3]);
    d4[1] = make_float4(acc[4],  acc[5],  acc[6],  acc[7]);
    d4[2] = make_float4(acc[8],  acc[9],  acc[10], acc[11]);
    d4[3] = make_float4(acc[12], acc[13], acc[14], acc[15]);
}

extern "C" void kernel_launch(void* const* d_in, const int* in_sizes, int n_in,
                              void* d_out, int out_size, void* d_ws, size_t ws_size,
                              hipStream_t stream) {
    const float* in   = (const float*)d_in[0];
    const float* wgt  = (const float*)d_in[1];
    const float* bias = (const float*)d_in[2];
    float* out = (float*)d_out;
    float* wt  = (float*)d_ws;   // 27*16*16 floats = 27648 B

    wt_transpose<<<27, 256, 0, stream>>>(wgt, wt);

    // level: R, base voxel offset; all R^3 divisible by 256
    conv_level<16><<<dim3(16,   4), 256, 0, stream>>>(in, wt, bias, out, 0);
    conv_level<32><<<dim3(128,  4), 256, 0, stream>>>(in, wt, bias, out, 4096);
    conv_level<48><<<dim3(432,  4), 256, 0, stream>>>(in, wt, bias, out, 36864);
    conv_level<64><<<dim3(1024, 4), 256, 0, stream>>>(in, wt, bias, out, 147456);
}

// Round 4
// 282.150 us; speedup vs baseline: 1.5308x; 1.5308x over previous
//
#include <hip/hip_runtime.h>

#define N_TOTAL 409600

typedef short short8 __attribute__((ext_vector_type(8)));
typedef float floatx4 __attribute__((ext_vector_type(4)));

__device__ __forceinline__ unsigned short f2bf(float f) {
    unsigned u = __float_as_uint(f);
    u += 0x7fffu + ((u >> 16) & 1u);
    return (unsigned short)(u >> 16);
}

// ---------- weight prepack: w[Cout][Cin][3][3][3] -> MFMA B-fragments ----------
// Pair p covers taps {2p, 2p+1}; k = tapSel*16 + ci. Lane l holds B[k][col]:
// col = l&15, k = (l>>4)*8 + j  (j = 0..7). Pair 13's upper half (tap 27) = 0.
__global__ __launch_bounds__(256) void wt_pack(const float* __restrict__ w,
                                               unsigned short* __restrict__ wtf) {
    int i = blockIdx.x * 256 + threadIdx.x;   // 14*64*8 = 7168
    if (i >= 7168) return;
    int j    = i & 7;
    int lane = (i >> 3) & 63;
    int p    = i >> 9;
    int q    = lane >> 4;
    int tap  = 2 * p + (q >> 1);
    int ci   = (q & 1) * 8 + j;
    int co   = lane & 15;
    float v  = (tap < 27) ? w[(co * 16 + ci) * 27 + tap] : 0.0f;
    wtf[(p * 64 + lane) * 8 + j] = f2bf(v);
}

// ---------- fp32 -> zero-padded (R+2)^3 bf16 grid ----------
// Thread handles 8 channels (half a voxel): fully coalesced 16B stores.
template <int R>
__global__ __launch_bounds__(256) void pad_bf16(const float* __restrict__ in,
                                                unsigned short* __restrict__ dst,
                                                int vbase) {
    constexpr int Rp   = R + 2;
    constexpr int nPad = Rp * Rp * Rp;
    int tid = blockIdx.x * 256 + threadIdx.x;
    if (tid >= nPad * 2) return;
    int half = tid & 1;
    int p    = tid >> 1;
    int b    = blockIdx.y;
    int pw = p % Rp, ph = (p / Rp) % Rp, pd = p / (Rp * Rp);

    short8 o = {0, 0, 0, 0, 0, 0, 0, 0};
    if (pw >= 1 && pw <= R && ph >= 1 && ph <= R && pd >= 1 && pd <= R) {
        int v = (((pd - 1) * R) + (ph - 1)) * R + (pw - 1);
        const float* src = in + ((size_t)(b * N_TOTAL + vbase) + v) * 16 + half * 8;
        float4 a0 = ((const float4*)src)[0];
        float4 a1 = ((const float4*)src)[1];
        o[0] = (short)f2bf(a0.x); o[1] = (short)f2bf(a0.y);
        o[2] = (short)f2bf(a0.z); o[3] = (short)f2bf(a0.w);
        o[4] = (short)f2bf(a1.x); o[5] = (short)f2bf(a1.y);
        o[6] = (short)f2bf(a1.z); o[7] = (short)f2bf(a1.w);
    }
    *(short8*)(dst + ((size_t)b * nPad + p) * 16 + half * 8) = o;
}

// ---------- main: implicit GEMM, one wave = 16 voxels x 16 cout ----------
template <int R>
__device__ __forceinline__ constexpr int tapOff(int t) {
    constexpr int Rp = R + 2;
    int kd = t / 9, kh = (t / 3) % 3, kw = t % 3;
    return (((kd - 1) * Rp + (kh - 1)) * Rp + (kw - 1)) * 16;
}

template <int R>
__global__ __launch_bounds__(256) void conv_mfma(const unsigned short* __restrict__ grid,
                                                 const unsigned short* __restrict__ wtf,
                                                 const float* __restrict__ bias,
                                                 float* __restrict__ out,
                                                 int vbase) {
    constexpr int Rp   = R + 2;
    constexpr int nPad = Rp * Rp * Rp;
    const int lane = threadIdx.x & 63;
    const int wave = threadIdx.x >> 6;
    const int b    = blockIdx.y;

    const int tile   = blockIdx.x * 4 + wave;
    const int voxel0 = tile * 16;             // 16 consecutive voxels (one w-segment)
    const int d  = voxel0 / (R * R);
    const int h  = (voxel0 / R) % R;
    const int w0 = voxel0 % R;

    const int q      = lane >> 4;
    const int r      = lane & 15;             // A-row: voxel; also C/D col: cout
    const int tapSel = q >> 1;
    const int ciHalf = (q & 1) * 8;

    // B fragments: 14 x 16B, L2-broadcast
    short8 bf[14];
#pragma unroll
    for (int p = 0; p < 14; ++p)
        bf[p] = *(const short8*)(wtf + (p * 64 + lane) * 8);

    // per-lane base address in padded grid (elements)
    const unsigned short* base =
        grid + (size_t)b * nPad * 16 +
        ((((size_t)(d + 1) * Rp + (h + 1)) * Rp + (w0 + 1)) + r) * 16 + ciHalf;

    const float bv = bias[r];
    floatx4 acc = {bv, bv, bv, bv};

#pragma unroll
    for (int p = 0; p < 14; ++p) {
        const int t1  = (2 * p + 1 < 27) ? 2 * p + 1 : 26;   // pair-13 upper half: B=0
        const int o0  = tapOff<R>(2 * p);
        const int o1  = tapOff<R>(t1);
        const int off = tapSel ? o1 : o0;
        short8 a = *(const short8*)(base + off);
        acc = __builtin_amdgcn_mfma_f32_16x16x32_bf16(a, bf[p], acc, 0, 0, 0);
    }

    const size_t outBase = ((size_t)b * N_TOTAL + vbase + voxel0) * 16;
#pragma unroll
    for (int j = 0; j < 4; ++j) {
        int row = q * 4 + j;                  // voxel within tile
        out[outBase + (size_t)row * 16 + r] = acc[j];
    }
}

// ---------- fp32 fallback (R1 kernel) in case ws_size is too small ----------
__global__ __launch_bounds__(256) void wt_transpose(const float* __restrict__ w,
                                                    float* __restrict__ wt) {
    int i = blockIdx.x * 256 + threadIdx.x;
    if (i < 6912) {
        int co = i / 432;
        int rr = i - co * 432;
        int ci = rr / 27;
        int tap = rr - ci * 27;
        wt[(tap * 16 + ci) * 16 + co] = w[i];
    }
}

template <int R>
__global__ __launch_bounds__(256) void conv_f32(const float* __restrict__ in,
                                                const float* __restrict__ wt,
                                                const float* __restrict__ bias,
                                                float* __restrict__ out, int base) {
    const int v = blockIdx.x * 256 + threadIdx.x;
    const int b = blockIdx.y;
    const int w = v % R, h = (v / R) % R, d = v / (R * R);
    const size_t lvl = ((size_t)b * N_TOTAL + base) * 16;
    const float* inp = in + lvl;
    float acc[16];
#pragma unroll
    for (int co = 0; co < 16; ++co) acc[co] = bias[co];
    for (int kd = 0; kd < 3; ++kd) {
        const int zd = d + kd - 1;
        if ((unsigned)zd >= (unsigned)R) continue;
        for (int kh = 0; kh < 3; ++kh) {
            const int zh = h + kh - 1;
            if ((unsigned)zh >= (unsigned)R) continue;
#pragma unroll
            for (int kw = 0; kw < 3; ++kw) {
                const int zw = w + kw - 1;
                if ((unsigned)zw >= (unsigned)R) continue;
                const float* src = inp + (size_t)(((zd * R + zh) * R) + zw) * 16;
                const float4* p4 = reinterpret_cast<const float4*>(src);
                float4 q0 = p4[0], q1 = p4[1], q2 = p4[2], q3 = p4[3];
                float x[16] = {q0.x, q0.y, q0.z, q0.w, q1.x, q1.y, q1.z, q1.w,
                               q2.x, q2.y, q2.z, q2.w, q3.x, q3.y, q3.z, q3.w};
                const float* wp = wt + ((kd * 3 + kh) * 3 + kw) * 256;
#pragma unroll
                for (int ci = 0; ci < 16; ++ci)
#pragma unroll
                    for (int co = 0; co < 16; ++co)
                        acc[co] = fmaf(x[ci], wp[ci * 16 + co], acc[co]);
            }
        }
    }
    float* dst = out + lvl + (size_t)v * 16;
    float4* d4 = reinterpret_cast<float4*>(dst);
    d4[0] = make_float4(acc[0], acc[1], acc[2], acc[3]);
    d4[1] = make_float4(acc[4], acc[5], acc[6], acc[7]);
    d4[2] = make_float4(acc[8], acc[9], acc[10], acc[11]);
    d4[3] = make_float4(acc[12], acc[13], acc[14], acc[15]);
}

extern "C" void kernel_launch(void* const* d_in, const int* in_sizes, int n_in,
                              void* d_out, int out_size, void* d_ws, size_t ws_size,
                              hipStream_t stream) {
    const float* in   = (const float*)d_in[0];
    const float* wgt  = (const float*)d_in[1];
    const float* bias = (const float*)d_in[2];
    float* out = (float*)d_out;

    // ws layout (bf16 elements): wtf [0,8192) | g16 | g32 | g48 | g64
    const size_t E16 = 8192;
    const size_t E32 = E16 + (size_t)4 * 5832 * 16;     // 381440
    const size_t E48 = E32 + (size_t)4 * 39304 * 16;    // 2896896
    const size_t E64 = E48 + (size_t)4 * 125000 * 16;   // 10896896
    const size_t END = E64 + (size_t)4 * 287496 * 16;   // 29296640 elems
    const size_t needed = END * sizeof(unsigned short); // ~58.6 MB

    if (ws_size >= needed) {
        unsigned short* ws16 = (unsigned short*)d_ws;
        unsigned short* wtf = ws16;
        unsigned short* g16 = ws16 + E16;
        unsigned short* g32 = ws16 + E32;
        unsigned short* g48 = ws16 + E48;
        unsigned short* g64 = ws16 + E64;

        wt_pack<<<28, 256, 0, stream>>>(wgt, wtf);
        pad_bf16<16><<<dim3(46,   4), 256, 0, stream>>>(in, g16, 0);
        pad_bf16<32><<<dim3(308,  4), 256, 0, stream>>>(in, g32, 4096);
        pad_bf16<48><<<dim3(977,  4), 256, 0, stream>>>(in, g48, 36864);
        pad_bf16<64><<<dim3(2247, 4), 256, 0, stream>>>(in, g64, 147456);

        conv_mfma<16><<<dim3(64,   4), 256, 0, stream>>>(g16, wtf, bias, out, 0);
        conv_mfma<32><<<dim3(512,  4), 256, 0, stream>>>(g32, wtf, bias, out, 4096);
        conv_mfma<48><<<dim3(1728, 4), 256, 0, stream>>>(g48, wtf, bias, out, 36864);
        conv_mfma<64><<<dim3(4096, 4), 256, 0, stream>>>(g64, wtf, bias, out, 147456);
    } else {
        float* wt = (float*)d_ws;   // 27648 B
        wt_transpose<<<27, 256, 0, stream>>>(wgt, wt);
        conv_f32<16><<<dim3(16,   4), 256, 0, stream>>>(in, wt, bias, out, 0);
        conv_f32<32><<<dim3(128,  4), 256, 0, stream>>>(in, wt, bias, out, 4096);
        conv_f32<48><<<dim3(432,  4), 256, 0, stream>>>(in, wt, bias, out, 36864);
        conv_f32<64><<<dim3(1024, 4), 256, 0, stream>>>(in, wt, bias, out, 147456);
    }
}

// Round 5
// 261.833 us; speedup vs baseline: 1.6495x; 1.0776x over previous
//
#include <hip/hip_runtime.h>

#define N_TOTAL 409600

typedef short short8 __attribute__((ext_vector_type(8)));
typedef float floatx4 __attribute__((ext_vector_type(4)));

__device__ __forceinline__ unsigned short f2bf(float f) {
    unsigned u = __float_as_uint(f);
    u += 0x7fffu + ((u >> 16) & 1u);
    return (unsigned short)(u >> 16);
}

// ws layout (bf16 elements): wtf [0,8192) | g16 | g32 | g48 | g64
#define E16 8192
#define E32 (E16 + (size_t)4 * 5832 * 16)
#define E48 (E32 + (size_t)4 * 39304 * 16)
#define E64 (E48 + (size_t)4 * 125000 * 16)
#define EEND (E64 + (size_t)4 * 287496 * 16)

// ---------------- merged pad (all levels) + weight pack ----------------
// Pad blocks per level: L16 46, L32 308, L48 977, L64 2247 -> 3578; +28 wt blocks.
template <int R>
__device__ __forceinline__ void pad_dev(const float* __restrict__ in,
                                        unsigned short* __restrict__ dst,
                                        int vbase, int tid, int b) {
    constexpr int Rp = R + 2;
    constexpr int nPad = Rp * Rp * Rp;
    if (tid >= nPad * 2) return;
    int half = tid & 1;
    int p = tid >> 1;
    int pw = p % Rp, ph = (p / Rp) % Rp, pd = p / (Rp * Rp);

    short8 o = {0, 0, 0, 0, 0, 0, 0, 0};
    if (pw >= 1 && pw <= R && ph >= 1 && ph <= R && pd >= 1 && pd <= R) {
        int v = (((pd - 1) * R) + (ph - 1)) * R + (pw - 1);
        const float* src = in + ((size_t)(b * N_TOTAL + vbase) + v) * 16 + half * 8;
        float4 a0 = ((const float4*)src)[0];
        float4 a1 = ((const float4*)src)[1];
        o[0] = (short)f2bf(a0.x); o[1] = (short)f2bf(a0.y);
        o[2] = (short)f2bf(a0.z); o[3] = (short)f2bf(a0.w);
        o[4] = (short)f2bf(a1.x); o[5] = (short)f2bf(a1.y);
        o[6] = (short)f2bf(a1.z); o[7] = (short)f2bf(a1.w);
    }
    *(short8*)(dst + ((size_t)b * nPad + p) * 16 + half * 8) = o;
}

__global__ __launch_bounds__(256) void pad_all(const float* __restrict__ in,
                                               const float* __restrict__ w,
                                               unsigned short* __restrict__ ws16) {
    const int bx = blockIdx.x;
    const int b  = blockIdx.y;
    if (bx < 46) {
        pad_dev<16>(in, ws16 + E16, 0, bx * 256 + threadIdx.x, b);
    } else if (bx < 354) {
        pad_dev<32>(in, ws16 + E32, 4096, (bx - 46) * 256 + threadIdx.x, b);
    } else if (bx < 1331) {
        pad_dev<48>(in, ws16 + E48, 36864, (bx - 354) * 256 + threadIdx.x, b);
    } else if (bx < 3578) {
        pad_dev<64>(in, ws16 + E64, 147456, (bx - 1331) * 256 + threadIdx.x, b);
    } else {
        // weight pack (duplicated across blockIdx.y; same values -> benign)
        int i = (bx - 3578) * 256 + threadIdx.x;   // 14*64*8 = 7168
        if (i >= 7168) return;
        int j    = i & 7;
        int lane = (i >> 3) & 63;
        int p    = i >> 9;
        int q    = lane >> 4;
        int tap  = 2 * p + (q >> 1);
        int ci   = (q & 1) * 8 + j;
        int co   = lane & 15;
        float v  = (tap < 27) ? w[(co * 16 + ci) * 27 + tap] : 0.0f;
        ws16[(p * 64 + lane) * 8 + j] = f2bf(v);
    }
}

// ---------------- merged conv (all levels), preloaded-ILP version ----------------
template <int R>
__device__ __forceinline__ constexpr int tapOff(int t) {
    constexpr int Rp = R + 2;
    int kd = t / 9, kh = (t / 3) % 3, kw = t % 3;
    return (((kd - 1) * Rp + (kh - 1)) * Rp + (kw - 1)) * 16;
}

template <int R>
__device__ __forceinline__ void conv_dev(const unsigned short* __restrict__ grid,
                                         const unsigned short* __restrict__ wtf,
                                         const float* __restrict__ bias,
                                         float* __restrict__ out,
                                         int vbase, int tile, int b) {
    constexpr int Rp = R + 2;
    constexpr int nPad = Rp * Rp * Rp;
    const int lane = threadIdx.x & 63;

    const int voxel0 = tile * 16;             // 16 consecutive voxels (one w-segment)
    const int d  = voxel0 / (R * R);
    const int h  = (voxel0 / R) % R;
    const int w0 = voxel0 % R;

    const int q      = lane >> 4;
    const int r      = lane & 15;             // A-row: voxel; C/D col: cout
    const int tapSel = q >> 1;
    const int ciHalf = (q & 1) * 8;

    const unsigned short* base =
        grid + (size_t)b * nPad * 16 +
        ((((size_t)(d + 1) * Rp + (h + 1)) * Rp + (w0 + 1)) + r) * 16 + ciHalf;

    // ---- preload ALL operands: 28 independent loads in flight ----
    short8 a[14];
#pragma unroll
    for (int p = 0; p < 14; ++p) {
        const int t1  = (2 * p + 1 < 27) ? 2 * p + 1 : 26;   // pair-13 upper half: B=0
        const int off = tapSel ? tapOff<R>(t1) : tapOff<R>(2 * p);
        a[p] = *(const short8*)(base + off);
    }
    short8 bf[14];
#pragma unroll
    for (int p = 0; p < 14; ++p)
        bf[p] = *(const short8*)(wtf + (p * 64 + lane) * 8);

    __builtin_amdgcn_sched_barrier(0);   // loads above, MFMAs below

    const float bv = bias[r];
    floatx4 acc = {bv, bv, bv, bv};
#pragma unroll
    for (int p = 0; p < 14; ++p)
        acc = __builtin_amdgcn_mfma_f32_16x16x32_bf16(a[p], bf[p], acc, 0, 0, 0);

    const size_t outBase = ((size_t)b * N_TOTAL + vbase + voxel0) * 16;
#pragma unroll
    for (int j = 0; j < 4; ++j) {
        int row = q * 4 + j;
        out[outBase + (size_t)row * 16 + r] = acc[j];
    }
}

// Conv blocks per level (4 tiles of 16 voxels per block):
// L16 64, L32 512, L48 1728, L64 4096 -> 6400 total.
__global__ __launch_bounds__(256, 2) void conv_all(const unsigned short* __restrict__ ws16,
                                                   const float* __restrict__ bias,
                                                   float* __restrict__ out) {
    const int bx   = blockIdx.x;
    const int b    = blockIdx.y;
    const int wave = threadIdx.x >> 6;
    const unsigned short* wtf = ws16;
    if (bx < 64) {
        conv_dev<16>(ws16 + E16, wtf, bias, out, 0,      bx * 4 + wave, b);
    } else if (bx < 576) {
        conv_dev<32>(ws16 + E32, wtf, bias, out, 4096,   (bx - 64) * 4 + wave, b);
    } else if (bx < 2304) {
        conv_dev<48>(ws16 + E48, wtf, bias, out, 36864,  (bx - 576) * 4 + wave, b);
    } else {
        conv_dev<64>(ws16 + E64, wtf, bias, out, 147456, (bx - 2304) * 4 + wave, b);
    }
}

// ---------------- fp32 fallback (small ws) ----------------
__global__ __launch_bounds__(256) void wt_transpose(const float* __restrict__ w,
                                                    float* __restrict__ wt) {
    int i = blockIdx.x * 256 + threadIdx.x;
    if (i < 6912) {
        int co = i / 432;
        int rr = i - co * 432;
        int ci = rr / 27;
        int tap = rr - ci * 27;
        wt[(tap * 16 + ci) * 16 + co] = w[i];
    }
}

template <int R>
__global__ __launch_bounds__(256) void conv_f32(const float* __restrict__ in,
                                                const float* __restrict__ wt,
                                                const float* __restrict__ bias,
                                                float* __restrict__ out, int base) {
    const int v = blockIdx.x * 256 + threadIdx.x;
    const int b = blockIdx.y;
    const int w = v % R, h = (v / R) % R, d = v / (R * R);
    const size_t lvl = ((size_t)b * N_TOTAL + base) * 16;
    const float* inp = in + lvl;
    float acc[16];
#pragma unroll
    for (int co = 0; co < 16; ++co) acc[co] = bias[co];
    for (int kd = 0; kd < 3; ++kd) {
        const int zd = d + kd - 1;
        if ((unsigned)zd >= (unsigned)R) continue;
        for (int kh = 0; kh < 3; ++kh) {
            const int zh = h + kh - 1;
            if ((unsigned)zh >= (unsigned)R) continue;
#pragma unroll
            for (int kw = 0; kw < 3; ++kw) {
                const int zw = w + kw - 1;
                if ((unsigned)zw >= (unsigned)R) continue;
                const float* src = inp + (size_t)(((zd * R + zh) * R) + zw) * 16;
                const float4* p4 = reinterpret_cast<const float4*>(src);
                float4 q0 = p4[0], q1 = p4[1], q2 = p4[2], q3 = p4[3];
                float x[16] = {q0.x, q0.y, q0.z, q0.w, q1.x, q1.y, q1.z, q1.w,
                               q2.x, q2.y, q2.z, q2.w, q3.x, q3.y, q3.z, q3.w};
                const float* wp = wt + ((kd * 3 + kh) * 3 + kw) * 256;
#pragma unroll
                for (int ci = 0; ci < 16; ++ci)
#pragma unroll
                    for (int co = 0; co < 16; ++co)
                        acc[co] = fmaf(x[ci], wp[ci * 16 + co], acc[co]);
            }
        }
    }
    float* dst = out + lvl + (size_t)v * 16;
    float4* d4 = reinterpret_cast<float4*>(dst);
    d4[0] = make_float4(acc[0], acc[1], acc[2], acc[3]);
    d4[1] = make_float4(acc[4], acc[5], acc[6], acc[7]);
    d4[2] = make_float4(acc[8], acc[9], acc[10], acc[11]);
    d4[3] = make_float4(acc[12], acc[13], acc[14], acc[15]);
}

extern "C" void kernel_launch(void* const* d_in, const int* in_sizes, int n_in,
                              void* d_out, int out_size, void* d_ws, size_t ws_size,
                              hipStream_t stream) {
    const float* in   = (const float*)d_in[0];
    const float* wgt  = (const float*)d_in[1];
    const float* bias = (const float*)d_in[2];
    float* out = (float*)d_out;

    const size_t needed = EEND * sizeof(unsigned short);   // ~58.6 MB

    if (ws_size >= needed) {
        unsigned short* ws16 = (unsigned short*)d_ws;
        pad_all <<<dim3(3606, 4), 256, 0, stream>>>(in, wgt, ws16);
        conv_all<<<dim3(6400, 4), 256, 0, stream>>>(ws16, bias, out);
    } else {
        float* wt = (float*)d_ws;   // 27648 B
        wt_transpose<<<27, 256, 0, stream>>>(wgt, wt);
        conv_f32<16><<<dim3(16,   4), 256, 0, stream>>>(in, wt, bias, out, 0);
        conv_f32<32><<<dim3(128,  4), 256, 0, stream>>>(in, wt, bias, out, 4096);
        conv_f32<48><<<dim3(432,  4), 256, 0, stream>>>(in, wt, bias, out, 36864);
        conv_f32<64><<<dim3(1024, 4), 256, 0, stream>>>(in, wt, bias, out, 147456);
    }
}